// Round 7
// baseline (121.385 us; speedup 1.0000x reference)
//
#include <hip/hip_runtime.h>
#include <hip/hip_fp16.h>
#include <math.h>

#define B_SZ 1024
#define N_SZ 128
#define M_SZ 256
#define I_SZ 64
#define NCH  16                // i-chunks (one per wave in main kernel)
#define CHI  (I_SZ / NCH)      // 4 i's per chunk

// one butterfly hop within 16-lane rows via DPP (VALU pipe, no DS)
template<int CTRL, typename OP>
__device__ __forceinline__ float dpp_hop(float x, OP op) {
    int yi = __builtin_amdgcn_update_dpp(0, __float_as_int(x), CTRL, 0xf, 0xf, true);
    return op(x, __int_as_float(yi));
}
struct MulOp { __device__ float operator()(float a, float b) const { return a * b; } };
struct AddOp { __device__ float operator()(float a, float b) const { return a + b; } };

// full 16-lane product: quad xor1, quad xor2, half_mirror(^7), mirror(^15)
__device__ __forceinline__ float prod16(float x) {
    x = dpp_hop<0xB1>(x, MulOp());
    x = dpp_hop<0x4E>(x, MulOp());
    x = dpp_hop<0x141>(x, MulOp());
    x = dpp_hop<0x140>(x, MulOp());
    return x;
}
__device__ __forceinline__ float sum16(float x) {
    x = dpp_hop<0xB1>(x, AddOp());
    x = dpp_hop<0x4E>(x, AddOp());
    x = dpp_hop<0x141>(x, AddOp());
    x = dpp_hop<0x140>(x, AddOp());
    return x;
}

// ---------------- kernel 1: prefix checkpoints + Sz flags ----------------
// grid 256 blocks x 256 thr; thread = m, block covers 4 b.
// Z[b][c][m] (fp16) = hb[m] + sum_{k<8c} vis[b,k]*W[m,k]
__global__ __launch_bounds__(256) void ck_kernel(
    const float* __restrict__ vis, const float* __restrict__ hb,
    const float* __restrict__ weight, __half* __restrict__ Z,
    float* __restrict__ flag)
{
    const int m  = threadIdx.x;
    const int b0 = blockIdx.x * 4;
    const float bias = hb[m];
    float z[4], sz[4];
    #pragma unroll
    for (int j = 0; j < 4; ++j) { z[j] = bias; sz[j] = 0.f; }

    for (int c = 0; c < NCH; ++c) {
        #pragma unroll
        for (int j = 0; j < 4; ++j)
            Z[((size_t)(b0 + j) * NCH + c) * M_SZ + m] = __float2half(z[j]);
        const float4 wa = *(const float4*)&weight[m * N_SZ + 8 * c];
        const float4 wb = *(const float4*)&weight[m * N_SZ + 8 * c + 4];
        #pragma unroll
        for (int j = 0; j < 4; ++j) {
            const float* vr = vis + (size_t)(b0 + j) * N_SZ + 8 * c; // uniform -> s_load
            const float a0 = vr[0], a1 = vr[1], a2 = vr[2], a3 = vr[3];
            const float a4 = vr[4], a5 = vr[5], a6 = vr[6], a7 = vr[7];
            z[j] += a0*wa.x + a1*wa.y + a2*wa.z + a3*wa.w
                  + a4*wb.x + a5*wb.y + a6*wb.z + a7*wb.w;
            sz[j] += (a0 - a1) + (a2 - a3) + (a4 - a5) + (a6 - a7);
        }
    }
    if (m == 0) {
        #pragma unroll
        for (int j = 0; j < 4; ++j)
            flag[b0 + j] = (sz[j] != 0.f) ? 0.f : 1.f;
    }
}

// ---------------- kernel 2: main ----------------
// grid 256 blocks x 1024 thr = 16 waves; wave wv = i-chunk [4wv, 4wv+4).
// Lane: bl = lane>>4 picks b, ml = lane&15; lane owns m = ml + 16t, t=0..15
// with a single running scalar zz per t. Per i: 3 __cosf per m; m-reduction
// = 4 DPP hops within 16-lane rows (VALU pipe, serves 4 b per instr).
// psi telescopes within the chunk: prod_i cos(full_i) = q0[1]*q0[2]*q0[3]*cos(z_end).
// NOTE: no min-waves in launch_bounds -> VGPR cap 128, body needs ~40 live: no spill.
__global__ __launch_bounds__(1024) void arrbm_main(
    const float* __restrict__ vis, const float* __restrict__ weight,
    const __half* __restrict__ Z, const float* __restrict__ flag,
    float* __restrict__ out)
{
    const int tid  = threadIdx.x;
    const int wv   = tid >> 6;          // chunk 0..15
    const int lane = tid & 63;
    const int bl   = lane >> 4, ml = lane & 15;
    const int b    = blockIdx.x * 4 + bl;
    const int i0   = wv * CHI;

    __shared__ float2 s_red[NCH][4];

    float v0[CHI], v1[CHI];
    #pragma unroll
    for (int j = 0; j < CHI; ++j) {
        const float2 vv = *(const float2*)&vis[(size_t)b * N_SZ + 2 * (i0 + j)];
        v0[j] = vv.x; v1[j] = vv.y;
    }

    float q0a[CHI], q1a[CHI], q2a[CHI];
    #pragma unroll
    for (int j = 0; j < CHI; ++j) { q0a[j] = 1.f; q1a[j] = 1.f; q2a[j] = 1.f; }
    float pend = 1.f;

    const __half* zrow = Z + ((size_t)b * NCH + wv) * M_SZ + ml;

    #pragma unroll
    for (int t = 0; t < 16; ++t) {
        float zz = __half2float(zrow[16 * t]);
        const float* wr = weight + (size_t)(ml + 16 * t) * N_SZ + 2 * i0;
        const float4 wa = *(const float4*)wr;        // (w0,w1) for i0, i0+1
        const float4 wb = *(const float4*)(wr + 4);  // (w0,w1) for i0+2, i0+3
        // j = 0
        q0a[0] *= __cosf(zz); q1a[0] *= __cosf(zz + wa.x); q2a[0] *= __cosf(zz + wa.y);
        zz += v0[0] * wa.x + v1[0] * wa.y;
        // j = 1
        q0a[1] *= __cosf(zz); q1a[1] *= __cosf(zz + wa.z); q2a[1] *= __cosf(zz + wa.w);
        zz += v0[1] * wa.z + v1[1] * wa.w;
        // j = 2
        q0a[2] *= __cosf(zz); q1a[2] *= __cosf(zz + wb.x); q2a[2] *= __cosf(zz + wb.y);
        zz += v0[2] * wb.x + v1[2] * wb.y;
        // j = 3
        q0a[3] *= __cosf(zz); q1a[3] *= __cosf(zz + wb.z); q2a[3] *= __cosf(zz + wb.w);
        zz += v0[3] * wb.z + v1[3] * wb.w;
        pend *= __cosf(zz);                          // cos(full at chunk end)
    }

    // 13 independent 16-lane product reductions, all on the VALU pipe via DPP
    #pragma unroll
    for (int j = 0; j < CHI; ++j) {
        q0a[j] = prod16(q0a[j]);
        q1a[j] = prod16(q1a[j]);
        q2a[j] = prod16(q2a[j]);
    }
    pend = prod16(pend);

    float acc = 1.f;
    #pragma unroll
    for (int j = 0; j < CHI; ++j)
        acc *= rsqrtf(4.f * q0a[j] * q0a[j] + 2.f * q1a[j] * q1a[j] + 2.f * q2a[j] * q2a[j]);
    float psi = pend;
    #pragma unroll
    for (int j = 1; j < CHI; ++j) psi *= q0a[j];

    if (ml == 0) s_red[wv][bl] = make_float2(psi, acc);
    __syncthreads();

    if (tid < 4) {
        float P = 1.f;
        #pragma unroll
        for (int w = 0; w < NCH; ++w) P *= s_red[w][tid].x * s_red[w][tid].y;
        out[blockIdx.x * 4 + tid] = P * flag[blockIdx.x * 4 + tid];
    }
}

extern "C" void kernel_launch(void* const* d_in, const int* in_sizes, int n_in,
                              void* d_out, int out_size, void* d_ws, size_t ws_size,
                              hipStream_t stream) {
    const float* vis    = (const float*)d_in[0];  // [B,N]
    const float* hb     = (const float*)d_in[1];  // [M]
    const float* weight = (const float*)d_in[2];  // [M,N]
    float* out = (float*)d_out;                   // [B]

    __half* Z   = (__half*)d_ws;                                  // 8 MB
    float* flag = (float*)((char*)d_ws +
                           (size_t)B_SZ * NCH * M_SZ * sizeof(__half));

    ck_kernel<<<B_SZ / 4, 256, 0, stream>>>(vis, hb, weight, Z, flag);
    arrbm_main<<<B_SZ / 4, 1024, 0, stream>>>(vis, weight, Z, flag, out);
}